// Round 8
// baseline (651.210 us; speedup 1.0000x reference)
//
#include <hip/hip_runtime.h>
#include <math.h>

#define NEGV -1e20f
#define DPAD 132      // diag row stride (s index)
#define RBOFF 16      // pad rows before row 0 (bwd prefetch reads to row -15)
#define ROWSA 676     // rows -16..659 (fwd prefetch reads to row 655)
#define RB(p,b) ((p) + ((size_t)(b) * ROWSA + RBOFF) * DPAD)
#define NROWS 77824   // 8*512*19 joiner rows

typedef __attribute__((ext_vector_type(4))) float floatx4;
typedef __attribute__((ext_vector_type(8))) short short8;

// B=8, T=512, S=128, C=512, S1=129, T1=513, R=19 (hard-coded for this problem)
// Diagonal-major DP arrays: X[b][d][s] = x[s][t] with d = s+t.

__device__ __forceinline__ float lae(float a, float b){
  float mx = fmaxf(a, b);
  float mn = fminf(a, b);
  return mx + __logf(1.f + __expf(mn - mx));   // exp underflows to 0 for big gaps
}

__device__ __forceinline__ short f2bf(float x){  // f32 -> bf16 RNE
  union { float f; unsigned u; } v; v.f = x;
  unsigned r = v.u + 0x7fffu + ((v.u >> 16) & 1u);
  return (short)(r >> 16);
}

__device__ __forceinline__ float tanh5(float x){   // 5 VALU ops, saturates correctly
  float e = __expf(2.f * x);
  return 1.f - 2.f * __builtin_amdgcn_rcpf(e + 1.f);
}

// ---------- per-row max (+ optional logsumexp) over C=512 ----------
__global__ __launch_bounds__(256) void k_row_stats(
    const float* __restrict__ in, float* __restrict__ outMax, float* __restrict__ outLse)
{
  int row = blockIdx.x;
  const float* r = in + (size_t)row * 512;
  int tid = threadIdx.x;
  float v0 = r[tid], v1 = r[tid + 256];
  float m = fmaxf(v0, v1);
  #pragma unroll
  for (int off = 32; off; off >>= 1) m = fmaxf(m, __shfl_xor(m, off, 64));
  __shared__ float sm[4];
  __shared__ float sbm;
  int wv = tid >> 6;
  if ((tid & 63) == 0) sm[wv] = m;
  __syncthreads();
  if (tid == 0) sbm = fmaxf(fmaxf(sm[0], sm[1]), fmaxf(sm[2], sm[3]));
  __syncthreads();
  float mx = sbm;
  if (tid == 0) outMax[row] = mx;
  if (outLse){
    float s = __expf(v0 - mx) + __expf(v1 - mx);
    #pragma unroll
    for (int off = 32; off; off >>= 1) s += __shfl_xor(s, off, 64);
    __shared__ float sp[4];
    if ((tid & 63) == 0) sp[wv] = s;
    __syncthreads();
    if (tid == 0) outLse[row] = mx + __logf(sp[0] + sp[1] + sp[2] + sp[3]);
  }
}

// ---------- transpose + bf16-convert joiner_w: Wb[d][c] = bf16(W[c][d]) ----------
__global__ __launch_bounds__(256) void k_wb(const float* __restrict__ W, short* __restrict__ Wb){
  int idx = blockIdx.x * 256 + threadIdx.x;   // 262144 total
  int d = idx >> 9, c = idx & 511;
  Wb[idx] = f2bf(W[c * 512 + d]);
}

// ---------- normalizers: norm[b,s,t] = log(dot(exp(lm-lmmax), exp(am-ammax))) + maxes ----------
__global__ __launch_bounds__(256) void k_norm(
    const float* __restrict__ am, const float* __restrict__ lm,
    const float* __restrict__ lmMax, const float* __restrict__ amMax,
    float* __restrict__ normv)
{
  int b = blockIdx.z;
  int s0 = blockIdx.y * 16;
  int t0 = blockIdx.x * 128;
  __shared__ float lmS[16][68];
  __shared__ float amS[128][68];
  int tid = threadIdx.x;
  int ts = tid >> 4, tt = tid & 15;
  float acc[8];
  #pragma unroll
  for (int j = 0; j < 8; ++j) acc[j] = 0.f;

  for (int k0 = 0; k0 < 512; k0 += 64){
    { // stage lm tile 16x64 (exp fused)
      int e = tid * 4;
      int rr = e >> 6, cc = e & 63;
      int s = s0 + rr;
      floatx4 o = {0.f, 0.f, 0.f, 0.f};
      if (s < 129){
        float mx = lmMax[b * 129 + s];
        floatx4 v = *(const floatx4*)(lm + ((size_t)(b * 129 + s)) * 512 + k0 + cc);
        o[0] = __expf(v[0] - mx); o[1] = __expf(v[1] - mx);
        o[2] = __expf(v[2] - mx); o[3] = __expf(v[3] - mx);
      }
      *(floatx4*)&lmS[rr][cc] = o;
    }
    #pragma unroll
    for (int i = 0; i < 8; ++i){ // stage am tile 128x64 (exp fused)
      int e = (tid + i * 256) * 4;
      int rr = e >> 6, cc = e & 63;
      float mx = amMax[b * 512 + t0 + rr];
      floatx4 v = *(const floatx4*)(am + ((size_t)(b * 512 + t0 + rr)) * 512 + k0 + cc);
      floatx4 o;
      o[0] = __expf(v[0] - mx); o[1] = __expf(v[1] - mx);
      o[2] = __expf(v[2] - mx); o[3] = __expf(v[3] - mx);
      *(floatx4*)&amS[rr][cc] = o;
    }
    __syncthreads();
    #pragma unroll 4
    for (int k = 0; k < 64; ++k){
      float a = lmS[ts][k];
      #pragma unroll
      for (int j = 0; j < 8; ++j) acc[j] += a * amS[tt + 16 * j][k];
    }
    __syncthreads();
  }
  int s = s0 + ts;
  if (s < 129){
    float lmx = lmMax[b * 129 + s];
    #pragma unroll
    for (int j = 0; j < 8; ++j){
      int t = t0 + tt + 16 * j;
      normv[((size_t)(b * 129 + s)) * 512 + t] = __logf(acc[j]) + lmx + amMax[b * 512 + t];
    }
  }
}

// ---------- smoothed px/py, written DIAG-major ----------
__global__ __launch_bounds__(256) void k_pxpy(
    const float* __restrict__ am, const float* __restrict__ lm,
    const int* __restrict__ targets, const float* __restrict__ normv,
    const float* __restrict__ lmLse, float* __restrict__ pxd, float* __restrict__ pyd)
{
  int bs = blockIdx.x;           // b*129 + s
  int b = bs / 129, s = bs % 129;
  float lm0 = lm[(size_t)bs * 512];
  float lse = lmLse[bs];
  int sym = 0; float lms = 0.f;
  if (s < 128){ sym = targets[b * 128 + s]; lms = lm[(size_t)bs * 512 + sym]; }
  const float* nrm = normv + (size_t)bs * 512;
  float* pydb = RB(pyd, b);
  float* pxdb = RB(pxd, b);
  for (int t = threadIdx.x; t < 513; t += 256){
    if (t < 512){
      float n = nrm[t];
      float a0 = am[((size_t)(b * 512 + t)) * 512];
      pydb[(size_t)(s + t) * DPAD + s] = 0.75f * (a0 + lm0 - n) + 0.25f * (lm0 - lse);
      if (s < 128){
        float as = am[((size_t)(b * 512 + t)) * 512 + sym];
        pxdb[(size_t)(s + t) * DPAD + s] = 0.75f * (as + lms - n) + 0.25f * (lms - lse);
      }
    } else if (s < 128){
      pxdb[(size_t)(s + 512) * DPAD + s] = NEGV;
    }
  }
}

// ======================================================================
// One-wave-per-batch systolic lattice DP (software-pipelined, static
// register double-buffers, one ds_bpermute per step, zero barriers).
// ======================================================================

__device__ __forceinline__ void dp_fwd_run(
    const float* __restrict__ pxb, const float* __restrict__ pyb,
    float* __restrict__ pab, float* __restrict__ tot, int b)
{
  int l = threadIdx.x;
  const int a = 2 * l;
  float curA = NEGV, curB = NEGV, curC = NEGV, send = NEGV;
  int paddr = (l - 1) << 2;

  float2 cpx = *(const float2*)(pxb - DPAD + a);
  float2 cpy = *(const float2*)(pyb - DPAD + a);
  float  cpz = pyb[-DPAD + 128];

  float2 b0px[8], b0py[8], b1px[8], b1py[8];
  float  b0pz[8], b1pz[8];
  float  outx[8], outy[8], outc[8];

  #pragma unroll
  for (int j = 0; j < 8; ++j){
    b0px[j] = *(const float2*)(pxb + (size_t)j * DPAD + a);
    b0py[j] = *(const float2*)(pyb + (size_t)j * DPAD + a);
    b0pz[j] = pyb[(size_t)j * DPAD + 128];
  }

  for (int i = 0; i < 40; ++i){
    int d0 = i * 16;
    #pragma unroll
    for (int j = 0; j < 8; ++j){
      b1px[j] = *(const float2*)(pxb + (size_t)(d0 + 8 + j) * DPAD + a);
      b1py[j] = *(const float2*)(pyb + (size_t)(d0 + 8 + j) * DPAD + a);
      b1pz[j] = pyb[(size_t)(d0 + 8 + j) * DPAD + 128];
    }
    #pragma unroll
    for (int j = 0; j < 8; ++j){
      int d = d0 + j;
      float2 pxm = j ? b0px[j - 1] : cpx;
      float2 pym = j ? b0py[j - 1] : cpy;
      float  pzm = j ? b0pz[j - 1] : cpz;
      float recv = __int_as_float(
          __builtin_amdgcn_ds_bpermute(paddr, __float_as_int(send)));
      int tA = d - a, tC = d - 128;
      float aaA = (l > 0) ? recv : NEGV;
      float bbA = (tA >= 1) ? curA + pym.x : NEGV;
      float nvA = lae(aaA, bbA);
      if (l == 0 && d == 0) nvA = 0.f;
      float aaB = curA + pxm.x;
      float bbB = (tA >= 2) ? curB + pym.y : NEGV;
      float nvB = lae(aaB, bbB);
      float aaC = curB + pxm.y;
      float bbC = (tC >= 1) ? curC + pzm : NEGV;
      float nvC = lae(aaC, bbC);
      if (tA >= 0 && tA <= 512) curA = nvA;
      if (tA >= 1 && tA <= 513) curB = nvB;
      if (tC >= 0 && tC <= 512) curC = nvC;
      send = curB + b0px[j].y;
      outx[j] = curA; outy[j] = curB; outc[j] = curC;
    }
    cpx = b0px[7]; cpy = b0py[7]; cpz = b0pz[7];
    if (pab){
      #pragma unroll
      for (int j = 0; j < 8; ++j)
        *(float2*)(pab + (size_t)(d0 + j) * DPAD + a) = make_float2(outx[j], outy[j]);
      if (l == 63){
        #pragma unroll
        for (int j = 0; j < 8; ++j)
          pab[(size_t)(d0 + j) * DPAD + 128] = outc[j];
      }
    }
    #pragma unroll
    for (int j = 0; j < 8; ++j){
      b0px[j] = *(const float2*)(pxb + (size_t)(d0 + 16 + j) * DPAD + a);
      b0py[j] = *(const float2*)(pyb + (size_t)(d0 + 16 + j) * DPAD + a);
      b0pz[j] = pyb[(size_t)(d0 + 16 + j) * DPAD + 128];
    }
    #pragma unroll
    for (int j = 0; j < 8; ++j){
      int d = d0 + 8 + j;
      float2 pxm = j ? b1px[j - 1] : cpx;
      float2 pym = j ? b1py[j - 1] : cpy;
      float  pzm = j ? b1pz[j - 1] : cpz;
      float recv = __int_as_float(
          __builtin_amdgcn_ds_bpermute(paddr, __float_as_int(send)));
      int tA = d - a, tC = d - 128;
      float aaA = (l > 0) ? recv : NEGV;
      float bbA = (tA >= 1) ? curA + pym.x : NEGV;
      float nvA = lae(aaA, bbA);
      float aaB = curA + pxm.x;
      float bbB = (tA >= 2) ? curB + pym.y : NEGV;
      float nvB = lae(aaB, bbB);
      float aaC = curB + pxm.y;
      float bbC = (tC >= 1) ? curC + pzm : NEGV;
      float nvC = lae(aaC, bbC);
      if (tA >= 0 && tA <= 512) curA = nvA;
      if (tA >= 1 && tA <= 513) curB = nvB;
      if (tC >= 0 && tC <= 512) curC = nvC;
      send = curB + b1px[j].y;
      outx[j] = curA; outy[j] = curB; outc[j] = curC;
    }
    cpx = b1px[7]; cpy = b1py[7]; cpz = b1pz[7];
    if (pab){
      #pragma unroll
      for (int j = 0; j < 8; ++j)
        *(float2*)(pab + (size_t)(d0 + 8 + j) * DPAD + a) = make_float2(outx[j], outy[j]);
      if (l == 63){
        #pragma unroll
        for (int j = 0; j < 8; ++j)
          pab[(size_t)(d0 + 8 + j) * DPAD + 128] = outc[j];
      }
    }
  }
  // tail: step 640
  {
    float aaC = curB + cpx.y;
    float bbC = curC + cpz;
    curC = lae(aaC, bbC);
    if (l == 63){
      if (pab) pab[(size_t)640 * DPAD + 128] = curC;
      tot[b] = curC;
    }
  }
}

__device__ __forceinline__ void dp_bwd_run(
    const float* __restrict__ pxb, const float* __restrict__ pyb,
    float* __restrict__ beb)
{
  int l = threadIdx.x;
  const int a = 2 * l;
  float curA = NEGV, curB = NEGV, curC = NEGV, send = NEGV;
  int paddr = (l + 1) << 2;

  float2 b0px[8], b0py[8], b1px[8], b1py[8];
  float  b0pz[8], b1pz[8];
  float  outx[8], outy[8], outc[8];

  #pragma unroll
  for (int j = 0; j < 8; ++j){
    b0px[j] = *(const float2*)(pxb + (size_t)(640 - j) * DPAD + a);
    b0py[j] = *(const float2*)(pyb + (size_t)(640 - j) * DPAD + a);
    b0pz[j] = pyb[(size_t)(640 - j) * DPAD + 128];
  }

  for (int i = 0; i < 40; ++i){
    int d0 = 640 - 16 * i;
    #pragma unroll
    for (int j = 0; j < 8; ++j){
      b1px[j] = *(const float2*)(pxb + (size_t)(d0 - 8 - j) * DPAD + a);
      b1py[j] = *(const float2*)(pyb + (size_t)(d0 - 8 - j) * DPAD + a);
      b1pz[j] = pyb[(size_t)(d0 - 8 - j) * DPAD + 128];
    }
    #pragma unroll
    for (int j = 0; j < 8; ++j){
      int d = d0 - j;
      float2 pxA = b0px[j]; float2 pyA = b0py[j]; float pzA = b0pz[j];
      float recv = __int_as_float(
          __builtin_amdgcn_ds_bpermute(paddr, __float_as_int(send)));
      int tA = d - a, tB = tA - 1, tC = d - 128;
      float aaA = pxA.x + curB;
      float bbA = (tA <= 511) ? pyA.x + curA : NEGV;
      float nvA = lae(aaA, bbA);
      float up = (l < 63) ? recv : curC;
      float aaB = pxA.y + up;
      float bbB = (tB <= 511) ? pyA.y + curB : NEGV;
      float nvB = lae(aaB, bbB);
      float nvC = (tC <= 511) ? pzA + curC : NEGV;
      if (tC == 512) nvC = 0.f;
      if (tA >= 0 && tA <= 512) curA = nvA;
      if (tB >= 0 && tB <= 512) curB = nvB;
      if (tC >= 0 && tC <= 512) curC = nvC;
      send = curA;
      outx[j] = curA; outy[j] = curB; outc[j] = curC;
    }
    #pragma unroll
    for (int j = 0; j < 8; ++j)
      *(float2*)(beb + (size_t)(d0 - j) * DPAD + a) = make_float2(outx[j], outy[j]);
    if (l == 63){
      #pragma unroll
      for (int j = 0; j < 8; ++j)
        beb[(size_t)(d0 - j) * DPAD + 128] = outc[j];
    }
    #pragma unroll
    for (int j = 0; j < 8; ++j){
      b0px[j] = *(const float2*)(pxb + (size_t)(d0 - 16 - j) * DPAD + a);
      b0py[j] = *(const float2*)(pyb + (size_t)(d0 - 16 - j) * DPAD + a);
      b0pz[j] = pyb[(size_t)(d0 - 16 - j) * DPAD + 128];
    }
    #pragma unroll
    for (int j = 0; j < 8; ++j){
      int d = d0 - 8 - j;
      float2 pxA = b1px[j]; float2 pyA = b1py[j]; float pzA = b1pz[j];
      float recv = __int_as_float(
          __builtin_amdgcn_ds_bpermute(paddr, __float_as_int(send)));
      int tA = d - a, tB = tA - 1, tC = d - 128;
      float aaA = pxA.x + curB;
      float bbA = (tA <= 511) ? pyA.x + curA : NEGV;
      float nvA = lae(aaA, bbA);
      float up = (l < 63) ? recv : curC;
      float aaB = pxA.y + up;
      float bbB = (tB <= 511) ? pyA.y + curB : NEGV;
      float nvB = lae(aaB, bbB);
      float nvC = (tC <= 511) ? pzA + curC : NEGV;
      if (tC == 512) nvC = 0.f;
      if (tA >= 0 && tA <= 512) curA = nvA;
      if (tB >= 0 && tB <= 512) curB = nvB;
      if (tC >= 0 && tC <= 512) curC = nvC;
      send = curA;
      outx[j] = curA; outy[j] = curB; outc[j] = curC;
    }
    #pragma unroll
    for (int j = 0; j < 8; ++j)
      *(float2*)(beb + (size_t)(d0 - 8 - j) * DPAD + a) = make_float2(outx[j], outy[j]);
    if (l == 63){
      #pragma unroll
      for (int j = 0; j < 8; ++j)
        beb[(size_t)(d0 - 8 - j) * DPAD + 128] = outc[j];
    }
  }
  // tail: step 0
  {
    float2 pxA = b0px[0]; float2 pyA = b0py[0];
    float recv = __int_as_float(
        __builtin_amdgcn_ds_bpermute(paddr, __float_as_int(send)));
    int tA = -a, tB = tA - 1;
    float aaA = pxA.x + curB;
    float bbA = (tA <= 511) ? pyA.x + curA : NEGV;
    float nvA = lae(aaA, bbA);
    float up = (l < 63) ? recv : curC;
    float aaB = pxA.y + up;
    float bbB = (tB <= 511) ? pyA.y + curB : NEGV;
    float nvB = lae(aaB, bbB);
    if (tA >= 0 && tA <= 512) curA = nvA;
    if (tB >= 0 && tB <= 512) curB = nvB;
    *(float2*)(beb + a) = make_float2(curA, curB);
    if (l == 63) beb[128] = curC;
  }
}

__global__ __launch_bounds__(64) void k_dp_fb(
    const float* __restrict__ pxd, const float* __restrict__ pyd,
    float* __restrict__ pad, float* __restrict__ betad, float* __restrict__ tots)
{
  int blk = blockIdx.x;
  if (blk < 8){
    int b = blk;
    dp_fwd_run(RB(pxd, b), RB(pyd, b), RB(pad, b), tots, b);
  } else {
    int b = blk - 8;
    dp_bwd_run(RB(pxd, b), RB(pyd, b), RB(betad, b));
  }
}

__global__ __launch_bounds__(64) void k_dp_f2(
    const float* __restrict__ pxd, const float* __restrict__ pyd,
    float* __restrict__ totp)
{
  int b = blockIdx.x;
  dp_fwd_run(RB(pxd, b), RB(pyd, b), (float*)nullptr, totp, b);
}

// ---------- sliding-window argmax over s for each (b,t); grads on the fly ----------
__global__ __launch_bounds__(256) void k_window(
    const float* __restrict__ pxd, const float* __restrict__ pyd,
    const float* __restrict__ pad, const float* __restrict__ betad,
    const float* __restrict__ tots, int* __restrict__ sbr)
{
  __shared__ float tote[129][66];
  int b = blockIdx.x >> 3;
  int t0 = (blockIdx.x & 7) << 6;
  const float* px = RB(pxd, b);
  const float* py = RB(pyd, b);
  const float* pa = RB(pad, b);
  const float* be = RB(betad, b);
  float tv = tots[b];
  int tid = threadIdx.x;
  int wv = tid >> 6, ln = tid & 63;
  for (int dd = wv; dd < 192; dd += 4){
    int d = t0 + dd;
    int slo = dd - 63 > 0 ? dd - 63 : 0;
    int shi = dd < 128 ? dd : 128;
    int s = slo + ln;
    if (s <= shi){
      size_t r0 = (size_t)d * DPAD + s, r1 = (size_t)(d + 1) * DPAD + s;
      float pav = pa[r0];
      float v = __expf(pav + py[r0] + be[r1] - tv);             // gy
      if (s < 128) v += __expf(pav + px[r0] + be[r1 + 1] - tv); // gx
      tote[s][dd - s] = v;
    }
  }
  __syncthreads();
  if (tid < 64){
    int c = tid;
    float win = 0.f;
    for (int s = 0; s < 19; ++s) win += tote[s][c];
    float best = win; int arg = 0;
    for (int w2 = 1; w2 <= 110; ++w2){
      win += tote[w2 + 18][c] - tote[w2 - 1][c];
      if (win > best){ best = win; arg = w2; }   // strict > keeps first-index argmax
    }
    sbr[b * 512 + t0 + c] = arg;
  }
}

// ---------- monotone lower-bound adjust (single reverse pass per batch) ----------
__global__ void k_adjust(const int* __restrict__ sbr, int* __restrict__ sbeg){
  if (threadIdx.x != 0) return;
  int b = blockIdx.x;
  const int* in = sbr + b * 512;
  int* out = sbeg + b * 512;
  int sbm = 1 << 30, ym = 1 << 30;
  for (int t = 511; t >= 0; --t){
    sbm = min(sbm, in[t]);
    int y = 18 * t - sbm;
    ym = min(ym, y);
    int yc = ym > 0 ? ym : 0;
    out[t] = 18 * t - yc;
  }
}

// ======================================================================
// joiner: k1 = materialize H bf16; k2 = LDS-free pipelined GEMM; k3 = norm.
// ======================================================================
__global__ __launch_bounds__(256) void k_stageH(
    const float* __restrict__ am, const float* __restrict__ lm,
    const int* __restrict__ sbeg, short* __restrict__ Hb)
{
  __shared__ int rowAm[64], rowLm[64];
  int tid = threadIdx.x;
  int r0 = blockIdx.x * 64;
  if (tid < 64){
    int row = r0 + tid;
    int g = row / 19;
    int j = row - g * 19;
    int b = g >> 9, t = g & 511;
    int sidx = sbeg[b * 512 + t] + j;
    rowAm[tid] = (b * 512 + t) * 512;
    rowLm[tid] = (b * 129 + sidx) * 512;
  }
  __syncthreads();
  int row = tid >> 2;              // 4 threads per row
  int kb = (tid & 3) * 8;
  const float* ap = am + (size_t)rowAm[row];
  const float* lp = lm + (size_t)rowLm[row];
  short* hp = Hb + (size_t)(r0 + row) * 512;
  #pragma unroll 4
  for (int i = 0; i < 16; ++i){
    int k = kb + i * 32;
    floatx4 a0 = *(const floatx4*)(ap + k);
    floatx4 a1 = *(const floatx4*)(ap + k + 4);
    floatx4 l0 = *(const floatx4*)(lp + k);
    floatx4 l1 = *(const floatx4*)(lp + k + 4);
    short8 h;
    h[0] = f2bf(tanh5(a0[0] + l0[0]));
    h[1] = f2bf(tanh5(a0[1] + l0[1]));
    h[2] = f2bf(tanh5(a0[2] + l0[2]));
    h[3] = f2bf(tanh5(a0[3] + l0[3]));
    h[4] = f2bf(tanh5(a1[0] + l1[0]));
    h[5] = f2bf(tanh5(a1[1] + l1[1]));
    h[6] = f2bf(tanh5(a1[2] + l1[2]));
    h[7] = f2bf(tanh5(a1[3] + l1[3]));
    *(short8*)(hp + k) = h;
  }
}

// k2: block = 128 rows x 128 cols; grid (4, 608) with nb FASTEST so the 4
// blocks sharing one A-row-panel are dispatched back-to-back (L2/L3 hot).
// Explicit 2-stage fragment double-buffer: prefetch k+32 while MFMA-ing k.
__global__ __launch_bounds__(256) void k_jgemm(
    const short* __restrict__ Hb, const short* __restrict__ Wb,
    const float* __restrict__ bias, const int* __restrict__ targets,
    const int* __restrict__ sbeg,
    float2* __restrict__ pms, float* __restrict__ pxraw, float* __restrict__ pyraw)
{
  __shared__ int rowSym[128];
  __shared__ float redM[128][2];
  __shared__ float redS[128][2];
  __shared__ float rowM[128];

  int tid = threadIdx.x;
  int nb = blockIdx.x;            // 0..3  (fastest -> A reuse across adjacent blocks)
  int rt = blockIdx.y;            // 0..607
  int r0 = rt * 128, c0 = nb * 128;
  if (tid < 128){
    int row = r0 + tid;
    int g = row / 19;
    int j = row - g * 19;
    int b = g >> 9, t = g & 511;
    int sidx = sbeg[b * 512 + t] + j;
    rowSym[tid] = (sidx < 128) ? targets[b * 128 + sidx] : 0;
  }
  __syncthreads();

  int w = tid >> 6, lane = tid & 63, q = lane >> 4, ln = lane & 15;
  int mBase = (w & 1) * 64;
  int nBase = (w >> 1) * 64;
  const short* Ab = Hb + (size_t)(r0 + mBase + ln) * 512 + q * 8;
  const short* Bb = Wb + (size_t)(c0 + nBase + ln) * 512 + q * 8;

  floatx4 acc[4][4];
  #pragma unroll
  for (int mt = 0; mt < 4; ++mt)
    #pragma unroll
    for (int nt = 0; nt < 4; ++nt) acc[mt][nt] = (floatx4){0.f, 0.f, 0.f, 0.f};

  short8 afA[4], bfA[4], afB[4], bfB[4];
  #pragma unroll
  for (int mt = 0; mt < 4; ++mt) afA[mt] = *(const short8*)(Ab + (size_t)mt * 16 * 512);
  #pragma unroll
  for (int nt = 0; nt < 4; ++nt) bfA[nt] = *(const short8*)(Bb + (size_t)nt * 16 * 512);

  for (int k0 = 0; k0 < 512; k0 += 64){
    // prefetch stage k0+32 while computing k0
    #pragma unroll
    for (int mt = 0; mt < 4; ++mt)
      afB[mt] = *(const short8*)(Ab + (size_t)mt * 16 * 512 + k0 + 32);
    #pragma unroll
    for (int nt = 0; nt < 4; ++nt)
      bfB[nt] = *(const short8*)(Bb + (size_t)nt * 16 * 512 + k0 + 32);
    #pragma unroll
    for (int nt = 0; nt < 4; ++nt)
      #pragma unroll
      for (int mt = 0; mt < 4; ++mt)
        acc[mt][nt] = __builtin_amdgcn_mfma_f32_16x16x32_bf16(afA[mt], bfA[nt], acc[mt][nt], 0, 0, 0);
    // prefetch stage k0+64 (last iter reads the pad) while computing k0+32
    #pragma unroll
    for (int mt = 0; mt < 4; ++mt)
      afA[mt] = *(const short8*)(Ab + (size_t)mt * 16 * 512 + k0 + 64);
    #pragma unroll
    for (int nt = 0; nt < 4; ++nt)
      bfA[nt] = *(const short8*)(Bb + (size_t)nt * 16 * 512 + k0 + 64);
    #pragma unroll
    for (int nt = 0; nt < 4; ++nt)
      #pragma unroll
      for (int mt = 0; mt < 4; ++mt)
        acc[mt][nt] = __builtin_amdgcn_mfma_f32_16x16x32_bf16(afB[mt], bfB[nt], acc[mt][nt], 0, 0, 0);
  }

  // bias + raw extraction + per-row partial max
  #pragma unroll
  for (int nt = 0; nt < 4; ++nt){
    int col = c0 + nBase + nt * 16 + ln;
    float bc = bias[col];
    #pragma unroll
    for (int mt = 0; mt < 4; ++mt)
      #pragma unroll
      for (int r = 0; r < 4; ++r){
        float v = acc[mt][nt][r] + bc;
        acc[mt][nt][r] = v;
        int rl = mBase + mt * 16 + q * 4 + r;
        if (col == 0) pyraw[r0 + rl] = v;
        if (col == rowSym[rl]) pxraw[r0 + rl] = v;
      }
  }
  #pragma unroll
  for (int mt = 0; mt < 4; ++mt)
    #pragma unroll
    for (int r = 0; r < 4; ++r){
      int rl = mBase + mt * 16 + q * 4 + r;
      float m = acc[mt][0][r];
      #pragma unroll
      for (int nt = 1; nt < 4; ++nt) m = fmaxf(m, acc[mt][nt][r]);
      m = fmaxf(m, __shfl_xor(m, 1, 16));
      m = fmaxf(m, __shfl_xor(m, 2, 16));
      m = fmaxf(m, __shfl_xor(m, 4, 16));
      m = fmaxf(m, __shfl_xor(m, 8, 16));
      if (ln == 0) redM[rl][w >> 1] = m;
    }
  __syncthreads();
  if (tid < 128) rowM[tid] = fmaxf(redM[tid][0], redM[tid][1]);
  __syncthreads();
  #pragma unroll
  for (int mt = 0; mt < 4; ++mt)
    #pragma unroll
    for (int r = 0; r < 4; ++r){
      int rl = mBase + mt * 16 + q * 4 + r;
      float rm = rowM[rl];
      float sa = 0.f;
      #pragma unroll
      for (int nt = 0; nt < 4; ++nt) sa += __expf(acc[mt][nt][r] - rm);
      sa += __shfl_xor(sa, 1, 16);
      sa += __shfl_xor(sa, 2, 16);
      sa += __shfl_xor(sa, 4, 16);
      sa += __shfl_xor(sa, 8, 16);
      if (ln == 0) redS[rl][w >> 1] = sa;
    }
  __syncthreads();
  if (tid < 128)
    pms[(size_t)nb * NROWS + r0 + tid] = make_float2(rowM[tid], redS[tid][0] + redS[tid][1]);
}

// ---------- joiner k3: combine partials, emit pxv/pyv ----------
__global__ __launch_bounds__(256) void k_jfin(
    const float2* __restrict__ pms, const float* __restrict__ pxraw,
    const float* __restrict__ pyraw, float* __restrict__ pxv, float* __restrict__ pyv)
{
  int row = blockIdx.x * 256 + threadIdx.x;
  float2 p0 = pms[row];
  float2 p1 = pms[NROWS + row];
  float2 p2 = pms[2 * NROWS + row];
  float2 p3 = pms[3 * NROWS + row];
  float M = fmaxf(fmaxf(p0.x, p1.x), fmaxf(p2.x, p3.x));
  float S = p0.y * __expf(p0.x - M) + p1.y * __expf(p1.x - M)
          + p2.y * __expf(p2.x - M) + p3.y * __expf(p3.x - M);
  float norm = M + __logf(S);
  pxv[row] = pxraw[row] - norm;
  pyv[row] = pyraw[row] - norm;
}

// ---------- scatter band values into diag-major px2d / py2d ----------
__global__ __launch_bounds__(192) void k_band(
    const float* __restrict__ pxv, const float* __restrict__ pyv,
    const int* __restrict__ sbeg, float* __restrict__ px2d, float* __restrict__ py2d)
{
  int bd = blockIdx.x;         // b*640 + d
  int b = bd / 640, d = bd - b * 640;
  int s = threadIdx.x;
  int t = d - s;
  if (s > 128 || t < 0 || t > 512) return;
  size_t addr = ((size_t)b * ROWSA + RBOFF + d) * DPAD + s;
  if (s < 128){
    float v;
    if (t == 512) v = NEGV;
    else {
      int start = sbeg[b * 512 + t];
      int j = s - start;
      v = (j >= 0 && j < 19) ? pxv[((size_t)(b * 512 + t)) * 19 + j] : NEGV;
    }
    px2d[addr] = v;
  }
  if (t <= 511){
    int start = sbeg[b * 512 + t];
    int j = s - start;
    py2d[addr] = (j >= 0 && j < 19) ? pyv[((size_t)(b * 512 + t)) * 19 + j] : NEGV;
  }
}

// ---------- final scalar ----------
__global__ void k_final(const float* __restrict__ tots, const float* __restrict__ totp,
                        float* __restrict__ out){
  if (blockIdx.x == 0 && threadIdx.x == 0){
    float a = 0.f, c = 0.f;
    for (int i = 0; i < 8; ++i){ a += tots[i]; c += totp[i]; }
    out[0] = -0.1f * (a * 0.125f) - (c * 0.125f);
  }
}

extern "C" void kernel_launch(void* const* d_in, const int* in_sizes, int n_in,
                              void* d_out, int out_size, void* d_ws, size_t ws_size,
                              hipStream_t stream){
  (void)in_sizes; (void)n_in; (void)out_size; (void)ws_size;
  const float* am      = (const float*)d_in[0];
  const float* lm      = (const float*)d_in[1];
  const int*   targets = (const int*)d_in[2];
  const float* W       = (const float*)d_in[4];
  const float* bias    = (const float*)d_in[5];
  float* out = (float*)d_out;

  char* base = (char*)d_ws;
  size_t off = 0;
  auto alloc = [&](size_t bytes) -> char* {
    char* r = base + off;
    off += (bytes + 255) & ~(size_t)255;
    return r;
  };
  const size_t DARR = 8ull * ROWSA * DPAD * 4;   // one diag-major array
  float* amMax = (float*)alloc(8ull * 512 * 4);
  float* lmMax = (float*)alloc(8ull * 129 * 4);
  float* lmLse = (float*)alloc(8ull * 129 * 4);
  float* normv = (float*)alloc(8ull * 129 * 512 * 4);
  float* pxd   = (float*)alloc(DARR);
  float* pyd   = (float*)alloc(DARR);
  float* pad   = (float*)alloc(DARR);
  float* betad = (float*)alloc(DARR);
  float* tots  = (float*)alloc(8 * 4);
  float* totp  = (float*)alloc(8 * 4);
  int*   sbr   = (int*)alloc(8ull * 512 * 4);
  int*   sbeg  = (int*)alloc(8ull * 512 * 4);
  float* pxv   = (float*)alloc((size_t)NROWS * 4);
  float* pyv   = (float*)alloc((size_t)NROWS * 4);
  short* Wb    = (short*)alloc((512ull * 512 + 512) * 2);        // +pad for prefetch
  short* Hb    = (short*)alloc(((size_t)NROWS * 512 + 512) * 2); // +pad for prefetch
  float2* pms  = (float2*)alloc(4ull * NROWS * 8);
  float* pxraw = (float*)alloc((size_t)NROWS * 4);
  float* pyraw = (float*)alloc((size_t)NROWS * 4);
  float* px2d  = pxd;   // alias: pxd/pyd dead after k_window
  float* py2d  = pyd;

  k_row_stats<<<dim3(4096), dim3(256), 0, stream>>>(am, amMax, (float*)nullptr);
  k_row_stats<<<dim3(1032), dim3(256), 0, stream>>>(lm, lmMax, lmLse);
  k_wb<<<dim3(1024), dim3(256), 0, stream>>>(W, Wb);
  k_norm<<<dim3(4, 9, 8), dim3(256), 0, stream>>>(am, lm, lmMax, amMax, normv);
  k_pxpy<<<dim3(1032), dim3(256), 0, stream>>>(am, lm, targets, normv, lmLse, pxd, pyd);
  k_dp_fb<<<dim3(16), dim3(64), 0, stream>>>(pxd, pyd, pad, betad, tots);
  k_window<<<dim3(64), dim3(256), 0, stream>>>(pxd, pyd, pad, betad, tots, sbr);
  k_adjust<<<dim3(8), dim3(64), 0, stream>>>(sbr, sbeg);
  k_stageH<<<dim3(1216), dim3(256), 0, stream>>>(am, lm, sbeg, Hb);
  k_jgemm<<<dim3(4, 608), dim3(256), 0, stream>>>(Hb, Wb, bias, targets, sbeg, pms, pxraw, pyraw);
  k_jfin<<<dim3(304), dim3(256), 0, stream>>>(pms, pxraw, pyraw, pxv, pyv);
  k_band<<<dim3(5120), dim3(192), 0, stream>>>(pxv, pyv, sbeg, px2d, py2d);
  k_dp_f2<<<dim3(8), dim3(64), 0, stream>>>(px2d, py2d, totp);
  k_final<<<dim3(1), dim3(64), 0, stream>>>(tots, totp, out);
}

// Round 9
// 554.658 us; speedup vs baseline: 1.1741x; 1.1741x over previous
//
#include <hip/hip_runtime.h>
#include <math.h>

#define NEGV -1e20f
#define DPAD 132      // diag row stride (s index)
#define RBOFF 16      // pad rows before row 0 (bwd prefetch reads to row -15)
#define ROWSA 676     // rows -16..659 (fwd prefetch reads to row 655)
#define RB(p,b) ((p) + ((size_t)(b) * ROWSA + RBOFF) * DPAD)
#define NROWS 77824   // 8*512*19 joiner rows

typedef __attribute__((ext_vector_type(4))) float floatx4;
typedef __attribute__((ext_vector_type(8))) short short8;

// B=8, T=512, S=128, C=512, S1=129, T1=513, R=19 (hard-coded for this problem)
// Diagonal-major DP arrays: X[b][d][s] = x[s][t] with d = s+t.

__device__ __forceinline__ float lae(float a, float b){
  float mx = fmaxf(a, b);
  float mn = fminf(a, b);
  return mx + __logf(1.f + __expf(mn - mx));   // exp underflows to 0 for big gaps
}

__device__ __forceinline__ short f2bf(float x){  // f32 -> bf16 RNE
  union { float f; unsigned u; } v; v.f = x;
  unsigned r = v.u + 0x7fffu + ((v.u >> 16) & 1u);
  return (short)(r >> 16);
}

__device__ __forceinline__ float tanh5(float x){   // 5 VALU ops, saturates correctly
  float e = __expf(2.f * x);
  return 1.f - 2.f * __builtin_amdgcn_rcpf(e + 1.f);
}

// async global->LDS, 16B per lane; LDS dest = wave-uniform base + lane*16 (CK-style casts)
__device__ __forceinline__ void gl_lds16(const short* __restrict__ g, short* l){
  __builtin_amdgcn_global_load_lds(
      (const __attribute__((address_space(1))) unsigned int*)g,
      (__attribute__((address_space(3))) unsigned int*)(unsigned long long)l,
      16, 0, 0);
}

// ---------- per-row max (+ optional logsumexp) over C=512 ----------
__global__ __launch_bounds__(256) void k_row_stats(
    const float* __restrict__ in, float* __restrict__ outMax, float* __restrict__ outLse)
{
  int row = blockIdx.x;
  const float* r = in + (size_t)row * 512;
  int tid = threadIdx.x;
  float v0 = r[tid], v1 = r[tid + 256];
  float m = fmaxf(v0, v1);
  #pragma unroll
  for (int off = 32; off; off >>= 1) m = fmaxf(m, __shfl_xor(m, off, 64));
  __shared__ float sm[4];
  __shared__ float sbm;
  int wv = tid >> 6;
  if ((tid & 63) == 0) sm[wv] = m;
  __syncthreads();
  if (tid == 0) sbm = fmaxf(fmaxf(sm[0], sm[1]), fmaxf(sm[2], sm[3]));
  __syncthreads();
  float mx = sbm;
  if (tid == 0) outMax[row] = mx;
  if (outLse){
    float s = __expf(v0 - mx) + __expf(v1 - mx);
    #pragma unroll
    for (int off = 32; off; off >>= 1) s += __shfl_xor(s, off, 64);
    __shared__ float sp[4];
    if ((tid & 63) == 0) sp[wv] = s;
    __syncthreads();
    if (tid == 0) outLse[row] = mx + __logf(sp[0] + sp[1] + sp[2] + sp[3]);
  }
}

// ---------- transpose + bf16-convert joiner_w: Wb[d][c] = bf16(W[c][d]) ----------
__global__ __launch_bounds__(256) void k_wb(const float* __restrict__ W, short* __restrict__ Wb){
  int idx = blockIdx.x * 256 + threadIdx.x;   // 262144 total
  int d = idx >> 9, c = idx & 511;
  Wb[idx] = f2bf(W[c * 512 + d]);
}

// ---------- normalizers: norm[b,s,t] = log(dot(exp(lm-lmmax), exp(am-ammax))) + maxes ----------
__global__ __launch_bounds__(256) void k_norm(
    const float* __restrict__ am, const float* __restrict__ lm,
    const float* __restrict__ lmMax, const float* __restrict__ amMax,
    float* __restrict__ normv)
{
  int b = blockIdx.z;
  int s0 = blockIdx.y * 16;
  int t0 = blockIdx.x * 128;
  __shared__ float lmS[16][68];
  __shared__ float amS[128][68];
  int tid = threadIdx.x;
  int ts = tid >> 4, tt = tid & 15;
  float acc[8];
  #pragma unroll
  for (int j = 0; j < 8; ++j) acc[j] = 0.f;

  for (int k0 = 0; k0 < 512; k0 += 64){
    { // stage lm tile 16x64 (exp fused)
      int e = tid * 4;
      int rr = e >> 6, cc = e & 63;
      int s = s0 + rr;
      floatx4 o = {0.f, 0.f, 0.f, 0.f};
      if (s < 129){
        float mx = lmMax[b * 129 + s];
        floatx4 v = *(const floatx4*)(lm + ((size_t)(b * 129 + s)) * 512 + k0 + cc);
        o[0] = __expf(v[0] - mx); o[1] = __expf(v[1] - mx);
        o[2] = __expf(v[2] - mx); o[3] = __expf(v[3] - mx);
      }
      *(floatx4*)&lmS[rr][cc] = o;
    }
    #pragma unroll
    for (int i = 0; i < 8; ++i){ // stage am tile 128x64 (exp fused)
      int e = (tid + i * 256) * 4;
      int rr = e >> 6, cc = e & 63;
      float mx = amMax[b * 512 + t0 + rr];
      floatx4 v = *(const floatx4*)(am + ((size_t)(b * 512 + t0 + rr)) * 512 + k0 + cc);
      floatx4 o;
      o[0] = __expf(v[0] - mx); o[1] = __expf(v[1] - mx);
      o[2] = __expf(v[2] - mx); o[3] = __expf(v[3] - mx);
      *(floatx4*)&amS[rr][cc] = o;
    }
    __syncthreads();
    #pragma unroll 4
    for (int k = 0; k < 64; ++k){
      float a = lmS[ts][k];
      #pragma unroll
      for (int j = 0; j < 8; ++j) acc[j] += a * amS[tt + 16 * j][k];
    }
    __syncthreads();
  }
  int s = s0 + ts;
  if (s < 129){
    float lmx = lmMax[b * 129 + s];
    #pragma unroll
    for (int j = 0; j < 8; ++j){
      int t = t0 + tt + 16 * j;
      normv[((size_t)(b * 129 + s)) * 512 + t] = __logf(acc[j]) + lmx + amMax[b * 512 + t];
    }
  }
}

// ---------- smoothed px/py, written DIAG-major ----------
__global__ __launch_bounds__(256) void k_pxpy(
    const float* __restrict__ am, const float* __restrict__ lm,
    const int* __restrict__ targets, const float* __restrict__ normv,
    const float* __restrict__ lmLse, float* __restrict__ pxd, float* __restrict__ pyd)
{
  int bs = blockIdx.x;           // b*129 + s
  int b = bs / 129, s = bs % 129;
  float lm0 = lm[(size_t)bs * 512];
  float lse = lmLse[bs];
  int sym = 0; float lms = 0.f;
  if (s < 128){ sym = targets[b * 128 + s]; lms = lm[(size_t)bs * 512 + sym]; }
  const float* nrm = normv + (size_t)bs * 512;
  float* pydb = RB(pyd, b);
  float* pxdb = RB(pxd, b);
  for (int t = threadIdx.x; t < 513; t += 256){
    if (t < 512){
      float n = nrm[t];
      float a0 = am[((size_t)(b * 512 + t)) * 512];
      pydb[(size_t)(s + t) * DPAD + s] = 0.75f * (a0 + lm0 - n) + 0.25f * (lm0 - lse);
      if (s < 128){
        float as = am[((size_t)(b * 512 + t)) * 512 + sym];
        pxdb[(size_t)(s + t) * DPAD + s] = 0.75f * (as + lms - n) + 0.25f * (lms - lse);
      }
    } else if (s < 128){
      pxdb[(size_t)(s + 512) * DPAD + s] = NEGV;
    }
  }
}

// ======================================================================
// One-wave-per-batch systolic lattice DP (software-pipelined, static
// register double-buffers, one ds_bpermute per step, zero barriers).
// ======================================================================

__device__ __forceinline__ void dp_fwd_run(
    const float* __restrict__ pxb, const float* __restrict__ pyb,
    float* __restrict__ pab, float* __restrict__ tot, int b)
{
  int l = threadIdx.x;
  const int a = 2 * l;
  float curA = NEGV, curB = NEGV, curC = NEGV, send = NEGV;
  int paddr = (l - 1) << 2;

  float2 cpx = *(const float2*)(pxb - DPAD + a);
  float2 cpy = *(const float2*)(pyb - DPAD + a);
  float  cpz = pyb[-DPAD + 128];

  float2 b0px[8], b0py[8], b1px[8], b1py[8];
  float  b0pz[8], b1pz[8];
  float  outx[8], outy[8], outc[8];

  #pragma unroll
  for (int j = 0; j < 8; ++j){
    b0px[j] = *(const float2*)(pxb + (size_t)j * DPAD + a);
    b0py[j] = *(const float2*)(pyb + (size_t)j * DPAD + a);
    b0pz[j] = pyb[(size_t)j * DPAD + 128];
  }

  for (int i = 0; i < 40; ++i){
    int d0 = i * 16;
    #pragma unroll
    for (int j = 0; j < 8; ++j){
      b1px[j] = *(const float2*)(pxb + (size_t)(d0 + 8 + j) * DPAD + a);
      b1py[j] = *(const float2*)(pyb + (size_t)(d0 + 8 + j) * DPAD + a);
      b1pz[j] = pyb[(size_t)(d0 + 8 + j) * DPAD + 128];
    }
    #pragma unroll
    for (int j = 0; j < 8; ++j){
      int d = d0 + j;
      float2 pxm = j ? b0px[j - 1] : cpx;
      float2 pym = j ? b0py[j - 1] : cpy;
      float  pzm = j ? b0pz[j - 1] : cpz;
      float recv = __int_as_float(
          __builtin_amdgcn_ds_bpermute(paddr, __float_as_int(send)));
      int tA = d - a, tC = d - 128;
      float aaA = (l > 0) ? recv : NEGV;
      float bbA = (tA >= 1) ? curA + pym.x : NEGV;
      float nvA = lae(aaA, bbA);
      if (l == 0 && d == 0) nvA = 0.f;
      float aaB = curA + pxm.x;
      float bbB = (tA >= 2) ? curB + pym.y : NEGV;
      float nvB = lae(aaB, bbB);
      float aaC = curB + pxm.y;
      float bbC = (tC >= 1) ? curC + pzm : NEGV;
      float nvC = lae(aaC, bbC);
      if (tA >= 0 && tA <= 512) curA = nvA;
      if (tA >= 1 && tA <= 513) curB = nvB;
      if (tC >= 0 && tC <= 512) curC = nvC;
      send = curB + b0px[j].y;
      outx[j] = curA; outy[j] = curB; outc[j] = curC;
    }
    cpx = b0px[7]; cpy = b0py[7]; cpz = b0pz[7];
    if (pab){
      #pragma unroll
      for (int j = 0; j < 8; ++j)
        *(float2*)(pab + (size_t)(d0 + j) * DPAD + a) = make_float2(outx[j], outy[j]);
      if (l == 63){
        #pragma unroll
        for (int j = 0; j < 8; ++j)
          pab[(size_t)(d0 + j) * DPAD + 128] = outc[j];
      }
    }
    #pragma unroll
    for (int j = 0; j < 8; ++j){
      b0px[j] = *(const float2*)(pxb + (size_t)(d0 + 16 + j) * DPAD + a);
      b0py[j] = *(const float2*)(pyb + (size_t)(d0 + 16 + j) * DPAD + a);
      b0pz[j] = pyb[(size_t)(d0 + 16 + j) * DPAD + 128];
    }
    #pragma unroll
    for (int j = 0; j < 8; ++j){
      int d = d0 + 8 + j;
      float2 pxm = j ? b1px[j - 1] : cpx;
      float2 pym = j ? b1py[j - 1] : cpy;
      float  pzm = j ? b1pz[j - 1] : cpz;
      float recv = __int_as_float(
          __builtin_amdgcn_ds_bpermute(paddr, __float_as_int(send)));
      int tA = d - a, tC = d - 128;
      float aaA = (l > 0) ? recv : NEGV;
      float bbA = (tA >= 1) ? curA + pym.x : NEGV;
      float nvA = lae(aaA, bbA);
      float aaB = curA + pxm.x;
      float bbB = (tA >= 2) ? curB + pym.y : NEGV;
      float nvB = lae(aaB, bbB);
      float aaC = curB + pxm.y;
      float bbC = (tC >= 1) ? curC + pzm : NEGV;
      float nvC = lae(aaC, bbC);
      if (tA >= 0 && tA <= 512) curA = nvA;
      if (tA >= 1 && tA <= 513) curB = nvB;
      if (tC >= 0 && tC <= 512) curC = nvC;
      send = curB + b1px[j].y;
      outx[j] = curA; outy[j] = curB; outc[j] = curC;
    }
    cpx = b1px[7]; cpy = b1py[7]; cpz = b1pz[7];
    if (pab){
      #pragma unroll
      for (int j = 0; j < 8; ++j)
        *(float2*)(pab + (size_t)(d0 + 8 + j) * DPAD + a) = make_float2(outx[j], outy[j]);
      if (l == 63){
        #pragma unroll
        for (int j = 0; j < 8; ++j)
          pab[(size_t)(d0 + 8 + j) * DPAD + 128] = outc[j];
      }
    }
  }
  // tail: step 640
  {
    float aaC = curB + cpx.y;
    float bbC = curC + cpz;
    curC = lae(aaC, bbC);
    if (l == 63){
      if (pab) pab[(size_t)640 * DPAD + 128] = curC;
      tot[b] = curC;
    }
  }
}

__device__ __forceinline__ void dp_bwd_run(
    const float* __restrict__ pxb, const float* __restrict__ pyb,
    float* __restrict__ beb)
{
  int l = threadIdx.x;
  const int a = 2 * l;
  float curA = NEGV, curB = NEGV, curC = NEGV, send = NEGV;
  int paddr = (l + 1) << 2;

  float2 b0px[8], b0py[8], b1px[8], b1py[8];
  float  b0pz[8], b1pz[8];
  float  outx[8], outy[8], outc[8];

  #pragma unroll
  for (int j = 0; j < 8; ++j){
    b0px[j] = *(const float2*)(pxb + (size_t)(640 - j) * DPAD + a);
    b0py[j] = *(const float2*)(pyb + (size_t)(640 - j) * DPAD + a);
    b0pz[j] = pyb[(size_t)(640 - j) * DPAD + 128];
  }

  for (int i = 0; i < 40; ++i){
    int d0 = 640 - 16 * i;
    #pragma unroll
    for (int j = 0; j < 8; ++j){
      b1px[j] = *(const float2*)(pxb + (size_t)(d0 - 8 - j) * DPAD + a);
      b1py[j] = *(const float2*)(pyb + (size_t)(d0 - 8 - j) * DPAD + a);
      b1pz[j] = pyb[(size_t)(d0 - 8 - j) * DPAD + 128];
    }
    #pragma unroll
    for (int j = 0; j < 8; ++j){
      int d = d0 - j;
      float2 pxA = b0px[j]; float2 pyA = b0py[j]; float pzA = b0pz[j];
      float recv = __int_as_float(
          __builtin_amdgcn_ds_bpermute(paddr, __float_as_int(send)));
      int tA = d - a, tB = tA - 1, tC = d - 128;
      float aaA = pxA.x + curB;
      float bbA = (tA <= 511) ? pyA.x + curA : NEGV;
      float nvA = lae(aaA, bbA);
      float up = (l < 63) ? recv : curC;
      float aaB = pxA.y + up;
      float bbB = (tB <= 511) ? pyA.y + curB : NEGV;
      float nvB = lae(aaB, bbB);
      float nvC = (tC <= 511) ? pzA + curC : NEGV;
      if (tC == 512) nvC = 0.f;
      if (tA >= 0 && tA <= 512) curA = nvA;
      if (tB >= 0 && tB <= 512) curB = nvB;
      if (tC >= 0 && tC <= 512) curC = nvC;
      send = curA;
      outx[j] = curA; outy[j] = curB; outc[j] = curC;
    }
    #pragma unroll
    for (int j = 0; j < 8; ++j)
      *(float2*)(beb + (size_t)(d0 - j) * DPAD + a) = make_float2(outx[j], outy[j]);
    if (l == 63){
      #pragma unroll
      for (int j = 0; j < 8; ++j)
        beb[(size_t)(d0 - j) * DPAD + 128] = outc[j];
    }
    #pragma unroll
    for (int j = 0; j < 8; ++j){
      b0px[j] = *(const float2*)(pxb + (size_t)(d0 - 16 - j) * DPAD + a);
      b0py[j] = *(const float2*)(pyb + (size_t)(d0 - 16 - j) * DPAD + a);
      b0pz[j] = pyb[(size_t)(d0 - 16 - j) * DPAD + 128];
    }
    #pragma unroll
    for (int j = 0; j < 8; ++j){
      int d = d0 - 8 - j;
      float2 pxA = b1px[j]; float2 pyA = b1py[j]; float pzA = b1pz[j];
      float recv = __int_as_float(
          __builtin_amdgcn_ds_bpermute(paddr, __float_as_int(send)));
      int tA = d - a, tB = tA - 1, tC = d - 128;
      float aaA = pxA.x + curB;
      float bbA = (tA <= 511) ? pyA.x + curA : NEGV;
      float nvA = lae(aaA, bbA);
      float up = (l < 63) ? recv : curC;
      float aaB = pxA.y + up;
      float bbB = (tB <= 511) ? pyA.y + curB : NEGV;
      float nvB = lae(aaB, bbB);
      float nvC = (tC <= 511) ? pzA + curC : NEGV;
      if (tC == 512) nvC = 0.f;
      if (tA >= 0 && tA <= 512) curA = nvA;
      if (tB >= 0 && tB <= 512) curB = nvB;
      if (tC >= 0 && tC <= 512) curC = nvC;
      send = curA;
      outx[j] = curA; outy[j] = curB; outc[j] = curC;
    }
    #pragma unroll
    for (int j = 0; j < 8; ++j)
      *(float2*)(beb + (size_t)(d0 - 8 - j) * DPAD + a) = make_float2(outx[j], outy[j]);
    if (l == 63){
      #pragma unroll
      for (int j = 0; j < 8; ++j)
        beb[(size_t)(d0 - 8 - j) * DPAD + 128] = outc[j];
    }
  }
  // tail: step 0
  {
    float2 pxA = b0px[0]; float2 pyA = b0py[0];
    float recv = __int_as_float(
        __builtin_amdgcn_ds_bpermute(paddr, __float_as_int(send)));
    int tA = -a, tB = tA - 1;
    float aaA = pxA.x + curB;
    float bbA = (tA <= 511) ? pyA.x + curA : NEGV;
    float nvA = lae(aaA, bbA);
    float up = (l < 63) ? recv : curC;
    float aaB = pxA.y + up;
    float bbB = (tB <= 511) ? pyA.y + curB : NEGV;
    float nvB = lae(aaB, bbB);
    if (tA >= 0 && tA <= 512) curA = nvA;
    if (tB >= 0 && tB <= 512) curB = nvB;
    *(float2*)(beb + a) = make_float2(curA, curB);
    if (l == 63) beb[128] = curC;
  }
}

__global__ __launch_bounds__(64) void k_dp_fb(
    const float* __restrict__ pxd, const float* __restrict__ pyd,
    float* __restrict__ pad, float* __restrict__ betad, float* __restrict__ tots)
{
  int blk = blockIdx.x;
  if (blk < 8){
    int b = blk;
    dp_fwd_run(RB(pxd, b), RB(pyd, b), RB(pad, b), tots, b);
  } else {
    int b = blk - 8;
    dp_bwd_run(RB(pxd, b), RB(pyd, b), RB(betad, b));
  }
}

__global__ __launch_bounds__(64) void k_dp_f2(
    const float* __restrict__ pxd, const float* __restrict__ pyd,
    float* __restrict__ totp)
{
  int b = blockIdx.x;
  dp_fwd_run(RB(pxd, b), RB(pyd, b), (float*)nullptr, totp, b);
}

// ---------- sliding-window argmax over s for each (b,t); grads on the fly ----------
__global__ __launch_bounds__(256) void k_window(
    const float* __restrict__ pxd, const float* __restrict__ pyd,
    const float* __restrict__ pad, const float* __restrict__ betad,
    const float* __restrict__ tots, int* __restrict__ sbr)
{
  __shared__ float tote[129][66];
  int b = blockIdx.x >> 3;
  int t0 = (blockIdx.x & 7) << 6;
  const float* px = RB(pxd, b);
  const float* py = RB(pyd, b);
  const float* pa = RB(pad, b);
  const float* be = RB(betad, b);
  float tv = tots[b];
  int tid = threadIdx.x;
  int wv = tid >> 6, ln = tid & 63;
  for (int dd = wv; dd < 192; dd += 4){
    int d = t0 + dd;
    int slo = dd - 63 > 0 ? dd - 63 : 0;
    int shi = dd < 128 ? dd : 128;
    int s = slo + ln;
    if (s <= shi){
      size_t r0 = (size_t)d * DPAD + s, r1 = (size_t)(d + 1) * DPAD + s;
      float pav = pa[r0];
      float v = __expf(pav + py[r0] + be[r1] - tv);             // gy
      if (s < 128) v += __expf(pav + px[r0] + be[r1 + 1] - tv); // gx
      tote[s][dd - s] = v;
    }
  }
  __syncthreads();
  if (tid < 64){
    int c = tid;
    float win = 0.f;
    for (int s = 0; s < 19; ++s) win += tote[s][c];
    float best = win; int arg = 0;
    for (int w2 = 1; w2 <= 110; ++w2){
      win += tote[w2 + 18][c] - tote[w2 - 1][c];
      if (win > best){ best = win; arg = w2; }   // strict > keeps first-index argmax
    }
    sbr[b * 512 + t0 + c] = arg;
  }
}

// ---------- monotone lower-bound adjust (single reverse pass per batch) ----------
__global__ void k_adjust(const int* __restrict__ sbr, int* __restrict__ sbeg){
  if (threadIdx.x != 0) return;
  int b = blockIdx.x;
  const int* in = sbr + b * 512;
  int* out = sbeg + b * 512;
  int sbm = 1 << 30, ym = 1 << 30;
  for (int t = 511; t >= 0; --t){
    sbm = min(sbm, in[t]);
    int y = 18 * t - sbm;
    ym = min(ym, y);
    int yc = ym > 0 ? ym : 0;
    out[t] = 18 * t - yc;
  }
}

// ======================================================================
// joiner: k1 = materialize H bf16; k2 = m97-style LDS GEMM; k3 = norm.
// ======================================================================
__global__ __launch_bounds__(256) void k_stageH(
    const float* __restrict__ am, const float* __restrict__ lm,
    const int* __restrict__ sbeg, short* __restrict__ Hb)
{
  __shared__ int rowAm[64], rowLm[64];
  int tid = threadIdx.x;
  int r0 = blockIdx.x * 64;
  if (tid < 64){
    int row = r0 + tid;
    int g = row / 19;
    int j = row - g * 19;
    int b = g >> 9, t = g & 511;
    int sidx = sbeg[b * 512 + t] + j;
    rowAm[tid] = (b * 512 + t) * 512;
    rowLm[tid] = (b * 129 + sidx) * 512;
  }
  __syncthreads();
  int row = tid >> 2;              // 4 threads per row
  int kb = (tid & 3) * 8;
  const float* ap = am + (size_t)rowAm[row];
  const float* lp = lm + (size_t)rowLm[row];
  short* hp = Hb + (size_t)(r0 + row) * 512;
  #pragma unroll 4
  for (int i = 0; i < 16; ++i){
    int k = kb + i * 32;
    floatx4 a0 = *(const floatx4*)(ap + k);
    floatx4 a1 = *(const floatx4*)(ap + k + 4);
    floatx4 l0 = *(const floatx4*)(lp + k);
    floatx4 l1 = *(const floatx4*)(lp + k + 4);
    short8 h;
    h[0] = f2bf(tanh5(a0[0] + l0[0]));
    h[1] = f2bf(tanh5(a0[1] + l0[1]));
    h[2] = f2bf(tanh5(a0[2] + l0[2]));
    h[3] = f2bf(tanh5(a0[3] + l0[3]));
    h[4] = f2bf(tanh5(a1[0] + l1[0]));
    h[5] = f2bf(tanh5(a1[1] + l1[1]));
    h[6] = f2bf(tanh5(a1[2] + l1[2]));
    h[7] = f2bf(tanh5(a1[3] + l1[3]));
    *(short8*)(hp + k) = h;
  }
}

// k2: m97-style. Block = 128x128, BK=32, single-buffered LDS (16KB),
// global_load_lds width=16 staging, 2 barriers/iter (staging for k+1
// overlaps MFMAs of k). XCD-aware swizzle: bid&7 = XCD; each XCD owns 76
// rt panels and runs the 4 nb blocks of one rt back-to-back -> A panel is
// HBM-fetched once, re-read from that XCD's L2. Wb (512KB) stays L2-hot.
__global__ __launch_bounds__(256) void k_jgemm(
    const short* __restrict__ Hb, const short* __restrict__ Wb,
    const float* __restrict__ bias, const int* __restrict__ targets,
    const int* __restrict__ sbeg,
    float2* __restrict__ pms, float* __restrict__ pxraw, float* __restrict__ pyraw)
{
  __shared__ short As[128 * 32];
  __shared__ short Bs[128 * 32];
  __shared__ int rowSym[128];
  __shared__ float redM[128][2];
  __shared__ float redS[128][2];
  __shared__ float rowM[128];

  int tid = threadIdx.x;
  int bid = blockIdx.x;
  int xcd = bid & 7, idx = bid >> 3;
  int nb = idx & 3;
  int rt = xcd * 76 + (idx >> 2);
  int r0 = rt * 128, c0 = nb * 128;

  if (tid < 128){
    int row = r0 + tid;
    int g = row / 19;
    int j = row - g * 19;
    int b = g >> 9, t = g & 511;
    int sidx = sbeg[b * 512 + t] + j;
    rowSym[tid] = (sidx < 128) ? targets[b * 128 + sidx] : 0;
  }

  int w = tid >> 6, lane = tid & 63, q = lane >> 4, ln = lane & 15;
  int mBase = (w & 1) * 64;
  int nBase = (w >> 1) * 64;

  // staging map: segment sg = (w*2+i)*64 + lane covers LDS [sg*8 .. sg*8+7]
  // = tile row sg>>2, shorts (sg&3)*8.. ; global = base + row*512 + k0 + (sg&3)*8
  int sg0 = (w * 2) * 64 + lane;
  int sRow0 = sg0 >> 2, sKp0 = (sg0 & 3) << 3;
  int sg1 = sg0 + 64;
  int sRow1 = sg1 >> 2, sKp1 = (sg1 & 3) << 3;
  const short* Ag = Hb + (size_t)r0 * 512;
  const short* Bg = Wb + (size_t)c0 * 512;
  short* AsB0 = As + (w * 2) * 512;      // wave-uniform LDS bases
  short* AsB1 = As + (w * 2 + 1) * 512;
  short* BsB0 = Bs + (w * 2) * 512;
  short* BsB1 = Bs + (w * 2 + 1) * 512;

  floatx4 acc[4][4];
  #pragma unroll
  for (int mt = 0; mt < 4; ++mt)
    #pragma unroll
    for (int nt = 0; nt < 4; ++nt) acc[mt][nt] = (floatx4){0.f, 0.f, 0.f, 0.f};

  for (int k0 = 0; k0 < 512; k0 += 32){
    gl_lds16(Ag + (size_t)sRow0 * 512 + k0 + sKp0, AsB0);
    gl_lds16(Ag + (size_t)sRow1 * 512 + k0 + sKp1, AsB1);
    gl_lds16(Bg + (size_t)sRow0 * 512 + k0 + sKp0, BsB0);
    gl_lds16(Bg + (size_t)sRow1 * 512 + k0 + sKp1, BsB1);
    __syncthreads();     // drains vmcnt (staging) + lgkm
    short8 af[4], bf[4];
    #pragma unroll
    for (int mt = 0; mt < 4; ++mt)
      af[mt] = *(const short8*)&As[(mBase + mt * 16 + ln) * 32 + q * 8];
    #pragma unroll
    for (int nt = 0; nt < 4; ++nt)
      bf[nt] = *(const short8*)&Bs[(nBase + nt * 16 + ln) * 32 + q * 8];
    __syncthreads();     // frags in regs; next staging may overwrite while we MFMA
    #pragma unroll
    for (int nt = 0; nt < 4; ++nt)
      #pragma unroll
      for (int mt = 0; mt < 4; ++mt)
        acc[mt][nt] = __builtin_amdgcn_mfma_f32_16x16x32_bf16(af[mt], bf[nt], acc[mt][nt], 0, 0, 0);
  }

  // bias + raw extraction + per-row partial max
  #pragma unroll
  for (int nt = 0; nt < 4; ++nt){
    int col = c0 + nBase + nt * 16 + ln;
    float bc = bias[col];
    #pragma unroll
    for (int mt = 0; mt < 4; ++mt)
      #pragma unroll
      for (int r = 0; r < 4; ++r){
        float v = acc[mt][nt][r] + bc;
        acc[mt][nt][r] = v;
        int rl = mBase + mt * 16 + q * 4 + r;
        if (col == 0) pyraw[r0 + rl] = v;
        if (col == rowSym[rl]) pxraw[r0 + rl] = v;
      }
  }
  #pragma unroll
  for (int mt = 0; mt < 4; ++mt)
    #pragma unroll
    for (int r = 0; r < 4; ++r){
      int rl = mBase + mt * 16 + q * 4 + r;
      float m = acc[mt][0][r];
      #pragma unroll
      for (int nt = 1; nt < 4; ++nt) m = fmaxf(m, acc[mt][nt][r]);
      m = fmaxf(m, __shfl_xor(m, 1, 16));
      m = fmaxf(m, __shfl_xor(m, 2, 16));
      m = fmaxf(m, __shfl_xor(m, 4, 16));
      m = fmaxf(m, __shfl_xor(m, 8, 16));
      if (ln == 0) redM[rl][w >> 1] = m;
    }
  __syncthreads();
  if (tid < 128) rowM[tid] = fmaxf(redM[tid][0], redM[tid][1]);
  __syncthreads();
  #pragma unroll
  for (int mt = 0; mt < 4; ++mt)
    #pragma unroll
    for (int r = 0; r < 4; ++r){
      int rl = mBase + mt * 16 + q * 4 + r;
      float rm = rowM[rl];
      float sa = 0.f;
      #pragma unroll
      for (int nt = 0; nt < 4; ++nt) sa += __expf(acc[mt][nt][r] - rm);
      sa += __shfl_xor(sa, 1, 16);
      sa += __shfl_xor(sa, 2, 16);
      sa += __shfl_xor(sa, 4, 16);
      sa += __shfl_xor(sa, 8, 16);
      if (ln == 0) redS[rl][w >> 1] = sa;
    }
  __syncthreads();
  if (tid < 128)
    pms[(size_t)nb * NROWS + r0 + tid] = make_float2(rowM[tid], redS[tid][0] + redS[tid][1]);
}

// ---------- joiner k3: combine partials, emit pxv/pyv ----------
__global__ __launch_bounds__(256) void k_jfin(
    const float2* __restrict__ pms, const float* __restrict__ pxraw,
    const float* __restrict__ pyraw, float* __restrict__ pxv, float* __restrict__ pyv)
{
  int row = blockIdx.x * 256 + threadIdx.x;
  float2 p0 = pms[row];
  float2 p1 = pms[NROWS + row];
  float2 p2 = pms[2 * NROWS + row];
  float2 p3 = pms[3 * NROWS + row];
  float M = fmaxf(fmaxf(p0.x, p1.x), fmaxf(p2.x, p3.x));
  float S = p0.y * __expf(p0.x - M) + p1.y * __expf(p1.x - M)
          + p2.y * __expf(p2.x - M) + p3.y * __expf(p3.x - M);
  float norm = M + __logf(S);
  pxv[row] = pxraw[row] - norm;
  pyv[row] = pyraw[row] - norm;
}

// ---------- scatter band values into diag-major px2d / py2d ----------
__global__ __launch_bounds__(192) void k_band(
    const float* __restrict__ pxv, const float* __restrict__ pyv,
    const int* __restrict__ sbeg, float* __restrict__ px2d, float* __restrict__ py2d)
{
  int bd = blockIdx.x;         // b*640 + d
  int b = bd / 640, d = bd - b * 640;
  int s = threadIdx.x;
  int t = d - s;
  if (s > 128 || t < 0 || t > 512) return;
  size_t addr = ((size_t)b * ROWSA + RBOFF + d) * DPAD + s;
  if (s < 128){
    float v;
    if (t == 512) v = NEGV;
    else {
      int start = sbeg[b * 512 + t];
      int j = s - start;
      v = (j >= 0 && j < 19) ? pxv[((size_t)(b * 512 + t)) * 19 + j] : NEGV;
    }
    px2d[addr] = v;
  }
  if (t <= 511){
    int start = sbeg[b * 512 + t];
    int j = s - start;
    py2d[addr] = (j >= 0 && j < 19) ? pyv[((size_t)(b * 512 + t)) * 19 + j] : NEGV;
  }
}

// ---------- final scalar ----------
__global__ void k_final(const float* __restrict__ tots, const float* __restrict__ totp,
                        float* __restrict__ out){
  if (blockIdx.x == 0 && threadIdx.x == 0){
    float a = 0.f, c = 0.f;
    for (int i = 0; i < 8; ++i){ a += tots[i]; c += totp[i]; }
    out[0] = -0.1f * (a * 0.125f) - (c * 0.125f);
  }
}

extern "C" void kernel_launch(void* const* d_in, const int* in_sizes, int n_in,
                              void* d_out, int out_size, void* d_ws, size_t ws_size,
                              hipStream_t stream){
  (void)in_sizes; (void)n_in; (void)out_size; (void)ws_size;
  const float* am      = (const float*)d_in[0];
  const float* lm      = (const float*)d_in[1];
  const int*   targets = (const int*)d_in[2];
  const float* W       = (const float*)d_in[4];
  const float* bias    = (const float*)d_in[5];
  float* out = (float*)d_out;

  char* base = (char*)d_ws;
  size_t off = 0;
  auto alloc = [&](size_t bytes) -> char* {
    char* r = base + off;
    off += (bytes + 255) & ~(size_t)255;
    return r;
  };
  const size_t DARR = 8ull * ROWSA * DPAD * 4;   // one diag-major array
  float* amMax = (float*)alloc(8ull * 512 * 4);
  float* lmMax = (float*)alloc(8ull * 129 * 4);
  float* lmLse = (float*)alloc(8ull * 129 * 4);
  float* normv = (float*)alloc(8ull * 129 * 512 * 4);
  float* pxd   = (float*)alloc(DARR);
  float* pyd   = (float*)alloc(DARR);
  float* pad   = (float*)alloc(DARR);
  float* betad = (float*)alloc(DARR);
  float* tots  = (float*)alloc(8 * 4);
  float* totp  = (float*)alloc(8 * 4);
  int*   sbr   = (int*)alloc(8ull * 512 * 4);
  int*   sbeg  = (int*)alloc(8ull * 512 * 4);
  float* pxv   = (float*)alloc((size_t)NROWS * 4);
  float* pyv   = (float*)alloc((size_t)NROWS * 4);
  short* Wb    = (short*)alloc((512ull * 512 + 512) * 2);        // +pad
  short* Hb    = (short*)alloc(((size_t)NROWS * 512 + 512) * 2); // +pad
  float2* pms  = (float2*)alloc(4ull * NROWS * 8);
  float* pxraw = (float*)alloc((size_t)NROWS * 4);
  float* pyraw = (float*)alloc((size_t)NROWS * 4);
  float* px2d  = pxd;   // alias: pxd/pyd dead after k_window
  float* py2d  = pyd;

  k_row_stats<<<dim3(4096), dim3(256), 0, stream>>>(am, amMax, (float*)nullptr);
  k_row_stats<<<dim3(1032), dim3(256), 0, stream>>>(lm, lmMax, lmLse);
  k_wb<<<dim3(1024), dim3(256), 0, stream>>>(W, Wb);
  k_norm<<<dim3(4, 9, 8), dim3(256), 0, stream>>>(am, lm, lmMax, amMax, normv);
  k_pxpy<<<dim3(1032), dim3(256), 0, stream>>>(am, lm, targets, normv, lmLse, pxd, pyd);
  k_dp_fb<<<dim3(16), dim3(64), 0, stream>>>(pxd, pyd, pad, betad, tots);
  k_window<<<dim3(64), dim3(256), 0, stream>>>(pxd, pyd, pad, betad, tots, sbr);
  k_adjust<<<dim3(8), dim3(64), 0, stream>>>(sbr, sbeg);
  k_stageH<<<dim3(1216), dim3(256), 0, stream>>>(am, lm, sbeg, Hb);
  k_jgemm<<<dim3(2432), dim3(256), 0, stream>>>(Hb, Wb, bias, targets, sbeg, pms, pxraw, pyraw);
  k_jfin<<<dim3(304), dim3(256), 0, stream>>>(pms, pxraw, pyraw, pxv, pyv);
  k_band<<<dim3(5120), dim3(192), 0, stream>>>(pxv, pyv, sbeg, px2d, py2d);
  k_dp_f2<<<dim3(8), dim3(64), 0, stream>>>(px2d, py2d, totp);
  k_final<<<dim3(1), dim3(64), 0, stream>>>(tots, totp, out);
}